// Round 12
// baseline (29.906 us; speedup 1.0000x reference)
//
#include <hip/hip_runtime.h>

#define NCAM   6
#define FHW    72        // FH*FW
#define EMBED  128
#define NG     432       // gaussians per scale
#define THRESH 0.01f
#define AMIN   (1.0f/255.0f)
#define NTILES 891
#define TC     432
// tiles are 4 rows x 16 cols:
// s0: 7x2=14 [0,14) H=25 | s1: 13x4=52 [14,66) H=50
// s2: 25x7=175 [66,241) H=100 | s3: 50x13=650 [241,891) H=200

struct Args {
    const float* feat[4];
    const float* mean[4];
    const float* unc[4];
    const float* opac[4];
};

__device__ __forceinline__ void tile_decode(int g, int& s, int& H, int& band, int& chunk)
{
    int tb;
    if (g < 14)       { s = 0; H = 25;  tb = g;       chunk = tb & 1;  band = tb >> 1; }
    else if (g < 66)  { s = 1; H = 50;  tb = g - 14;  chunk = tb & 3;  band = tb >> 2; }
    else if (g < 241) { s = 2; H = 100; tb = g - 66;  band = tb / 7;   chunk = tb - band * 7; }
    else              { s = 3; H = 200; tb = g - 241; band = tb / 13;  chunk = tb - band * 13; }
}

// K1: [0,24) ft transpose (scale x cam); 24: num_gaussians
__global__ __launch_bounds__(256) void prep(Args a, float* __restrict__ ft,
                                            float* __restrict__ out)
{
    int b = blockIdx.x, t = threadIdx.x;
    if (b < 24) {
        __shared__ float l[EMBED * 73];
        int s = b / NCAM, cam = b - s * NCAM;
        const float* src = a.feat[s] + cam * (EMBED * FHW);
        for (int i = t; i < EMBED * FHW; i += 256) {
            int d = i / FHW, hw = i - d * FHW;
            l[d * 73 + hw] = src[i];
        }
        __syncthreads();
        float* dst = ft + (s * NG + cam * FHW) * EMBED;
        for (int e = t; e < EMBED * FHW; e += 256) {
            int hw = e >> 7, d = e & 127;
            dst[hw * EMBED + d] = l[d * 73 + hw];
        }
    } else {
        __shared__ float red[256];
        float c = 0.f;
        for (int s = 0; s < 4; s++)
            for (int i = t; i < NG; i += 256)
                c += (a.opac[s][i] > THRESH) ? 1.f : 0.f;
        red[t] = c;
        __syncthreads();
        for (int st = 128; st > 0; st >>= 1) {
            if (t < st) red[t] += red[t + st];
            __syncthreads();
        }
        if (t == 0) out[6800000] = red[0];
    }
}

// K2: block = (tile g, ch-quarter chq). Prologue: in-block cull -> LDS param
// streams. Hot loop: 4 waves = 4 k-quarters, lane = pixel, dist-1 register
// pipeline (params from LDS, features issued one iteration early), register-only
// alpha/T/acc, no sync. Epilogue: exact prefix-T fix-up + cross-wave reduce
// (LDS union with param region).
__global__ __launch_bounds__(256) void render(Args a, const float* __restrict__ ft,
                                              float* __restrict__ out)
{
    __shared__ __align__(16) char smem[26368];   // e0|e1  /  s_T|s_part (union)
    __shared__ int s_cnt[8];
    float4* e0 = (float4*)smem;                  // [TC] pr,pc,qa,qb
    float4* e1 = (float4*)(smem + 6912);         // [TC] qc,ok,off,-

    int bb = blockIdx.x, t = threadIdx.x;
    int g = bb >> 2, chq = bb & 3;
    int s, H, band, chunk;
    tile_decode(g, s, H, band, chunk);
    int P = H * H;
    float* o = out + ((s == 0) ? 0 : (s == 1) ? 80000 : (s == 2) ? 400000 : 1680000);
    int lane = t & 63;
    int wv = __builtin_amdgcn_readfirstlane(t >> 6);
    float sh = H * 0.01f;
    float r0f = (float)(band * 4), r1f = (float)min(band * 4 + 3, H - 1);
    float c0f = (float)(chunk * 16), c1f = (float)min(chunk * 16 + 15, H - 1);
    const float* mean = a.mean[s];
    const float* unc  = a.unc[s];
    const float* opac = a.opac[s];

    // ---- cull prologue (ordered ballot compaction into LDS) ----
    bool v_act[2]; int v_rnk[2];
    float v_pr[2], v_pc[2], v_qa[2], v_qb[2], v_qc[2], v_ok[2];
    #pragma unroll
    for (int pp = 0; pp < 2; pp++) {
        int j = pp * 256 + t;
        bool act = false;
        float pr = 0.f, pc = 0.f, qa = 0.f, qb = 0.f, qc = 0.f, ok = 0.f;
        if (j < NG) {
            float m0 = mean[j*3+0], m1 = mean[j*3+1];
            float u00 = fmaxf(unc[j*9+0], 1.f);
            float u01 = fmaxf(unc[j*9+1], 1.f);
            float u11 = fmaxf(unc[j*9+4], 1.f);
            float op = opac[j];
            pr = -sh*m1 + H*0.5f;
            pc = -sh*m0 + H*0.5f;
            float va = sh*sh*u11 + 0.3f;
            float vb = sh*sh*u01;
            float vc = sh*sh*u00 + 0.3f;
            float det = va*vc - vb*vb;
            if (op > THRESH && det > 0.f) {
                float inv = 1.f/det;
                qa = 0.5f*vc*inv;                      // dr^2 coeff
                qc = 0.5f*va*inv;                      // dc^2 coeff
                qb = vb*inv;                           // dr*dc coeff
                ok = op;
                float thr = __logf(255.f*op);          // alpha >= 1/255 level set
                float Rr = sqrtf(2.f*va*thr) + 1e-2f;  // max |dr| on level set
                float Rc = sqrtf(2.f*vc*thr) + 1e-2f;  // max |dc| on level set
                act = (pr >= r0f-Rr) && (pr <= r1f+Rr) &&
                      (pc >= c0f-Rc) && (pc <= c1f+Rc);
            }
        }
        unsigned long long m = __ballot(act);
        v_act[pp] = act;
        v_rnk[pp] = __popcll(m & ((1ull << lane) - 1ull));
        v_pr[pp]=pr; v_pc[pp]=pc; v_qa[pp]=qa; v_qb[pp]=qb; v_qc[pp]=qc; v_ok[pp]=ok;
        if (lane == 0) s_cnt[pp*4 + wv] = __popcll(m);
    }
    __syncthreads();
    int c8[8];
    #pragma unroll
    for (int i = 0; i < 8; i++) c8[i] = s_cnt[i];
    int len = 0;
    #pragma unroll
    for (int i = 0; i < 8; i++) len += c8[i];
    #pragma unroll
    for (int pp = 0; pp < 2; pp++) {
        int slot = pp*4 + wv;
        int pre = 0;
        #pragma unroll
        for (int i = 0; i < 8; i++) pre += (i < slot) ? c8[i] : 0;
        if (v_act[pp]) {
            int idx = pre + v_rnk[pp];
            int j = pp * 256 + t;
            unsigned off = (unsigned)((s*NG + j) * EMBED);
            e0[idx] = make_float4(v_pr[pp], v_pc[pp], v_qa[pp], v_qb[pp]);
            e1[idx] = make_float4(v_qc[pp], v_ok[pp], __uint_as_float(off), 0.f);
        }
    }
    __syncthreads();

    // ---- hot loop: wave wv scans quarter [k0,k1v), dist-1 pipeline ----
    int qlen = (len + 3) >> 2;
    int k0 = wv * qlen, k1v = min(k0 + qlen, len);
    int ch0 = chq * 32;
    int row = band*4 + (lane >> 4), col = chunk*16 + (lane & 15);
    float frow = (float)row, fcol = (float)col;

    float acc[32];
    #pragma unroll
    for (int i = 0; i < 32; i++) acc[i] = 0.f;
    float T = 1.f;

    if (k0 < k1v) {
        float4 A = e0[k0], Bv = e1[k0];
        unsigned off0 = __builtin_amdgcn_readfirstlane(__float_as_uint(Bv.z));
        const float* fr = ft + off0 + ch0;
        float4 f[8];
        #pragma unroll
        for (int i = 0; i < 8; i++)
            f[i] = *reinterpret_cast<const float4*>(fr + i * 4);

        for (int k = k0; k < k1v; k++) {
            int kn = (k + 1 < k1v) ? k + 1 : k;
            float4 An = e0[kn], Bn = e1[kn];       // LDS broadcast, early issue
            float dr = A.x - frow, dc = A.y - fcol;
            float pw = A.w*dr*dc - A.z*dr*dr - Bv.x*dc*dc;
            float aL = 0.f;
            if (pw <= 0.f) {
                aL = fminf(Bv.y * __expf(pw), 0.99f);
                aL = (aL >= AMIN) ? aL : 0.f;
            }
            float w = aL * T;
            T *= (1.f - aL);
            #pragma unroll
            for (int i = 0; i < 8; i++) {          // consume current features
                acc[i*4]   += w * f[i].x;
                acc[i*4+1] += w * f[i].y;
                acc[i*4+2] += w * f[i].z;
                acc[i*4+3] += w * f[i].w;
            }
            unsigned offn = __builtin_amdgcn_readfirstlane(__float_as_uint(Bn.z));
            const float* frn = ft + offn + ch0;
            #pragma unroll
            for (int i = 0; i < 8; i++)            // issue next-iter features
                f[i] = *reinterpret_cast<const float4*>(frn + i * 4);
            A = An; Bv = Bn;
        }
    }

    // ---- epilogue: prefix-T fix-up + cross-wave reduce (smem reused) ----
    __syncthreads();                               // all e0/e1 readers done
    float* s_T    = (float*)smem;                  // [4][64]
    float* s_part = (float*)(smem + 1024);         // [3][64][33]
    s_T[wv * 64 + lane] = T;
    __syncthreads();
    if (wv > 0) {
        float pref = s_T[lane];
        if (wv > 1) pref *= s_T[64 + lane];
        if (wv > 2) pref *= s_T[128 + lane];
        #pragma unroll
        for (int i = 0; i < 32; i++)
            s_part[(wv - 1) * 2112 + lane * 33 + i] = acc[i] * pref;
    }
    __syncthreads();
    if (wv == 0 && row < H && col < H) {
        int pp = row * H + col;
        #pragma unroll
        for (int i = 0; i < 32; i++) {
            float v = acc[i] + s_part[lane * 33 + i]
                             + s_part[2112 + lane * 33 + i]
                             + s_part[4224 + lane * 33 + i];
            o[(ch0 + i) * P + pp] = v;
        }
    }
}

extern "C" void kernel_launch(void* const* d_in, const int* in_sizes, int n_in,
                              void* d_out, int out_size, void* d_ws, size_t ws_size,
                              hipStream_t stream)
{
    Args a;
    for (int s = 0; s < 4; s++) {
        a.feat[s] = (const float*)d_in[4 * s + 0];
        a.mean[s] = (const float*)d_in[4 * s + 1];
        a.unc[s]  = (const float*)d_in[4 * s + 2];
        a.opac[s] = (const float*)d_in[4 * s + 3];
    }
    float* ws = (float*)d_ws;
    float* ft = ws;                                // 221,184 floats

    prep<<<25, 256, 0, stream>>>(a, ft, (float*)d_out);
    render<<<NTILES * 4, 256, 0, stream>>>(a, ft, (float*)d_out);
}